// Round 2
// baseline (439.774 us; speedup 1.0000x reference)
//
#include <hip/hip_runtime.h>
#include <math.h>

// Problem constants
#define B_    32
#define S_    2048
#define CIN_  256
#define COUT_ 256
#define K_    16
#define TOUT_ 2033   // S - K + 1
#define RTOT_ 4096   // CIN * K reduction length

typedef __bf16 bf16x8 __attribute__((ext_vector_type(8)));
typedef float  f32x4  __attribute__((ext_vector_type(4)));

#define GLOBAL_AS __attribute__((address_space(1)))
#define LDS_AS    __attribute__((address_space(3)))

__device__ __forceinline__ void gload_lds16(const void* g, void* l) {
  // async global -> LDS: per-lane global gather, LDS dest = wave-uniform base + lane*16
  __builtin_amdgcn_global_load_lds((const GLOBAL_AS void*)g, (LDS_AS void*)l, 16, 0, 0);
}

// ---------------------------------------------------------------------------
// Build B^T in bf16:  wt[o][kk*256 + i] = cos(ph[kk])*w_real[o][i][kk]
//                                        - sin(ph[kk])*w_imag[o][i][kk]
// Row-major [COUT][RTOT] = 2 MB — the only workspace use.
// Reduction index r = kk*256 + i matches the A-tile chunking (c = kk*8 + i/32).
// ---------------------------------------------------------------------------
__global__ void __launch_bounds__(256) build_wt_kernel(const float* __restrict__ wr,
                                                       const float* __restrict__ wi,
                                                       const float* __restrict__ ph,
                                                       __bf16* __restrict__ wt) {
  int t = blockIdx.x * 256 + threadIdx.x;   // 65536 threads: one per (o,i)
  int o = t >> 8, i = t & 255;
  const float4* wr4 = (const float4*)(wr + (size_t)(o * CIN_ + i) * K_);
  const float4* wi4 = (const float4*)(wi + (size_t)(o * CIN_ + i) * K_);
  float re[16], im[16];
  #pragma unroll
  for (int v = 0; v < 4; v++) {
    float4 a = wr4[v];
    re[4*v+0]=a.x; re[4*v+1]=a.y; re[4*v+2]=a.z; re[4*v+3]=a.w;
    float4 b = wi4[v];
    im[4*v+0]=b.x; im[4*v+1]=b.y; im[4*v+2]=b.z; im[4*v+3]=b.w;
  }
  #pragma unroll
  for (int kk = 0; kk < K_; kk++) {
    float p = ph[kk];
    wt[(size_t)o * RTOT_ + kk * CIN_ + i] = (__bf16)(cosf(p)*re[kk] - sinf(p)*im[kk]);
  }
}

// ---------------------------------------------------------------------------
// Main: m97-structure implicit-GEMM conv, B^T layout (the ref-checked pattern).
// Block = 256 threads (4 waves, 2x2), C-tile 128x128 (t x o), BK=32,
// 128 chunks: chunk c -> tap kk = c>>3, channels i0 = (c&7)*32.
// A staged as fp32 (x used directly, no pre-conversion), cvt to bf16 at
// fragment build. B^T staged as bf16, read exactly like A (gemm_bt geometry).
// ---------------------------------------------------------------------------
__global__ void __launch_bounds__(256) conv_mfma_kernel(const float* __restrict__ xg,
                                                        const __bf16* __restrict__ wt,
                                                        float* __restrict__ out) {
  __shared__ __align__(16) float  Asf[128 * 32];  // [row t][32 ch] fp32, 16 KB
  __shared__ __align__(16) __bf16 Bs [128 * 32];  // [row o][32 k ] bf16,  8 KB

  const int bx = blockIdx.x;
  const int nb = bx & 1;          // o-block 0..1
  const int mb = (bx >> 1) & 15;  // t-block 0..15
  const int b  = bx >> 5;         // batch   0..31

  const int tid  = threadIdx.x;
  const int w    = tid >> 6;
  const int lane = tid & 63;
  const int wm   = w >> 1, wn = w & 1;
  const int n16  = lane & 15, q = lane >> 4;

  const int t0 = mb * 128;
  const int o0 = nb * 128;

  const float* xbase = xg + (size_t)b * (S_ * CIN_);

  // A staging (fp32, 16 KB, 16 issues): issue p, wave w covers rows p*32+w*8..+8
  const int ar = w * 8 + (lane >> 3);   // row within a 32-row group
  const int ac = (lane & 7) * 4;        // fp32 col offset (4 floats / lane)
  // B staging (bf16, 8 KB, 8 issues): issue p, wave w covers rows p*64+w*16..+16
  const int br = w * 16 + (lane >> 2);
  const int bc = (lane & 3) * 8;        // bf16 col offset (8 bf16 / lane)

  f32x4 acc[4][4];
  #pragma unroll
  for (int im_ = 0; im_ < 4; im_++)
    #pragma unroll
    for (int in_ = 0; in_ < 4; in_++)
      acc[im_][in_] = {0.f, 0.f, 0.f, 0.f};

  for (int c = 0; c < 128; ++c) {
    const int kk = c >> 3;
    const int i0 = (c & 7) * 32;

    __syncthreads();  // previous chunk's LDS reads complete

    // ---- A tile: x[t0+kk+row][i0..i0+32) fp32 ----
    #pragma unroll
    for (int p = 0; p < 4; p++) {
      int r = t0 + kk + p * 32 + ar;
      r = (r < S_) ? r : (S_ - 1);  // clamp: garbage only feeds masked C rows
      gload_lds16(xbase + (size_t)r * CIN_ + i0 + ac,
                  (void*)(Asf + (p * 32 + w * 8) * 32));
    }
    // ---- B tile: wt[o0+row][c*32 .. c*32+32) bf16 ----
    #pragma unroll
    for (int p = 0; p < 2; p++) {
      int orow = o0 + p * 64 + br;
      gload_lds16(wt + (size_t)orow * RTOT_ + c * 32 + bc,
                  (void*)(Bs + (p * 64 + w * 16) * 32));
    }

    __syncthreads();  // drains vmcnt: LDS tiles valid

    bf16x8 af[4], bfrag[4];
    #pragma unroll
    for (int jm = 0; jm < 4; jm++) {
      int row = wm * 64 + jm * 16 + n16;          // A[m=lane&15][k=q*8+j]
      const float* src = Asf + row * 32 + q * 8;
      f32x4 lo = *(const f32x4*)src;
      f32x4 hi = *(const f32x4*)(src + 4);
      bf16x8 v;
      v[0] = (__bf16)lo[0]; v[1] = (__bf16)lo[1]; v[2] = (__bf16)lo[2]; v[3] = (__bf16)lo[3];
      v[4] = (__bf16)hi[0]; v[5] = (__bf16)hi[1]; v[6] = (__bf16)hi[2]; v[7] = (__bf16)hi[3];
      af[jm] = v;
    }
    #pragma unroll
    for (int jn = 0; jn < 4; jn++) {
      int row = wn * 64 + jn * 16 + n16;          // B^T[n=lane&15][k=q*8+j]
      bfrag[jn] = *(const bf16x8*)(Bs + row * 32 + q * 8);
    }
    #pragma unroll
    for (int jm = 0; jm < 4; jm++)
      #pragma unroll
      for (int jn = 0; jn < 4; jn++)
        acc[jm][jn] = __builtin_amdgcn_mfma_f32_16x16x32_bf16(af[jm], bfrag[jn], acc[jm][jn], 0, 0, 0);
  }

  // ---- Epilogue: C/D layout col = lane&15, row = (lane>>4)*4 + reg ----
  float* obase = out + (size_t)b * TOUT_ * COUT_;
  #pragma unroll
  for (int jm = 0; jm < 4; jm++) {
    #pragma unroll
    for (int r = 0; r < 4; r++) {
      int t = t0 + wm * 64 + jm * 16 + q * 4 + r;
      if (t < TOUT_) {
        float* orow = obase + (size_t)t * COUT_ + o0 + wn * 64 + n16;
        #pragma unroll
        for (int jn = 0; jn < 4; jn++)
          orow[jn * 16] = acc[jm][jn][r];
      }
    }
  }
}

// ---------------------------------------------------------------------------
extern "C" void kernel_launch(void* const* d_in, const int* in_sizes, int n_in,
                              void* d_out, int out_size, void* d_ws, size_t ws_size,
                              hipStream_t stream) {
  const float* x  = (const float*)d_in[0];
  const float* wr = (const float*)d_in[1];
  const float* wi = (const float*)d_in[2];
  const float* ph = (const float*)d_in[3];
  float* out = (float*)d_out;

  __bf16* wt = (__bf16*)d_ws;  // 2 MB only

  build_wt_kernel<<<dim3((COUT_ * CIN_) / 256), dim3(256), 0, stream>>>(wr, wi, ph, wt);
  conv_mfma_kernel<<<dim3(B_ * 16 * 2), dim3(256), 0, stream>>>(x, wt, out);
}

// Round 3
// 234.876 us; speedup vs baseline: 1.8724x; 1.8724x over previous
//
#include <hip/hip_runtime.h>
#include <math.h>

// Problem constants
#define B_    32
#define S_    2048
#define CIN_  256
#define COUT_ 256
#define K_    16
#define TOUT_ 2033   // S - K + 1
#define RTOT_ 4096   // CIN * K reduction length

typedef __bf16 bf16x4 __attribute__((ext_vector_type(4)));
typedef __bf16 bf16x8 __attribute__((ext_vector_type(8)));
typedef float  f32x4  __attribute__((ext_vector_type(4)));

#define GLOBAL_AS __attribute__((address_space(1)))
#define LDS_AS    __attribute__((address_space(3)))

__device__ __forceinline__ void gload_lds16(const void* g, void* l) {
  // async global -> LDS: per-lane global gather, LDS dest = wave-uniform base + lane*16
  __builtin_amdgcn_global_load_lds((const GLOBAL_AS void*)g, (LDS_AS void*)l, 16, 0, 0);
}

// ---------------------------------------------------------------------------
// Build B^T in bf16:  wt[o][kk*256 + i] = cos(ph[kk])*w_real[o][i][kk]
//                                        - sin(ph[kk])*w_imag[o][i][kk]
// Row-major [COUT][RTOT] = 2 MB — the only workspace use (round-1 evidence
// says large ws allocations are unsafe; keep ws footprint tiny).
// ---------------------------------------------------------------------------
__global__ void __launch_bounds__(256) build_wt_kernel(const float* __restrict__ wr,
                                                       const float* __restrict__ wi,
                                                       const float* __restrict__ ph,
                                                       __bf16* __restrict__ wt) {
  int t = blockIdx.x * 256 + threadIdx.x;   // 65536 threads: one per (o,i)
  int o = t >> 8, i = t & 255;
  const float4* wr4 = (const float4*)(wr + (size_t)(o * CIN_ + i) * K_);
  const float4* wi4 = (const float4*)(wi + (size_t)(o * CIN_ + i) * K_);
  float re[16], im[16];
  #pragma unroll
  for (int v = 0; v < 4; v++) {
    float4 a = wr4[v];
    re[4*v+0]=a.x; re[4*v+1]=a.y; re[4*v+2]=a.z; re[4*v+3]=a.w;
    float4 b = wi4[v];
    im[4*v+0]=b.x; im[4*v+1]=b.y; im[4*v+2]=b.z; im[4*v+3]=b.w;
  }
  #pragma unroll
  for (int kk = 0; kk < K_; kk++) {
    float p = ph[kk];
    wt[(size_t)o * RTOT_ + kk * CIN_ + i] = (__bf16)(cosf(p)*re[kk] - sinf(p)*im[kk]);
  }
}

// ---------------------------------------------------------------------------
// Main: implicit-GEMM conv with tap-resident A tile.
// Block = 256 threads (4 waves, 2x2), C-tile 128x128 (t x o).
// Outer loop ic (8 channel groups of 32): stage A = x[t0 .. t0+143][ic*32..+32)
//   ONCE (fp32 load -> cvt -> bf16 LDS, m97 row-stride-32 layout, 9 KB).
// Inner loop kk (16 taps): stage B chunk wt[o0..+128)[kk*256+ic*32 ..+32)
//   (8 KB bf16 via global_load_lds); A fragments read at LDS row offset +kk.
// A global traffic: 147 KB/block (16x less than streaming im2col).
// ---------------------------------------------------------------------------
__global__ void __launch_bounds__(256) conv_mfma_kernel(const float* __restrict__ xg,
                                                        const __bf16* __restrict__ wt,
                                                        float* __restrict__ out) {
  __shared__ __align__(16) __bf16 As[144 * 32];  // [row t-local][32 ch] 9 KB
  __shared__ __align__(16) __bf16 Bs[128 * 32];  // [row o-local][32 k ] 8 KB

  const int bx = blockIdx.x;
  const int nb = bx & 1;          // o-block 0..1
  const int mb = (bx >> 1) & 15;  // t-block 0..15
  const int b  = bx >> 5;         // batch   0..31

  const int tid  = threadIdx.x;
  const int w    = tid >> 6;
  const int lane = tid & 63;
  const int wm   = w >> 1, wn = w & 1;
  const int n16  = lane & 15, q = lane >> 4;

  const int t0 = mb * 128;
  const int o0 = nb * 128;

  const float* xbase = xg + (size_t)b * (S_ * CIN_);

  // A staging geometry (reg round-trip): thread -> (row sr, 4 fp32 at col sc)
  const int sr = tid >> 3;        // 0..31
  const int sc = (tid & 7) * 4;   // fp32/bf16 col offset
  // B staging geometry (global_load_lds, 16B/lane): wave w, issue p covers
  // rows p*64 + w*16 .. +16
  const int br = w * 16 + (lane >> 2);
  const int bc = (lane & 3) * 8;

  f32x4 acc[4][4];
  #pragma unroll
  for (int im_ = 0; im_ < 4; im_++)
    #pragma unroll
    for (int in_ = 0; in_ < 4; in_++)
      acc[im_][in_] = {0.f, 0.f, 0.f, 0.f};

  for (int ic = 0; ic < 8; ++ic) {
    const int i0 = ic * 32;

    __syncthreads();  // previous ic's As reads + previous kk's Bs reads done

    // ---- Stage A: rows 0..143 (= x rows t0..t0+143, clamped), 32 ch ----
    {
      const float* xcol = xbase + i0 + sc;
      #pragma unroll
      for (int p = 0; p < 4; p++) {
        int r = p * 32 + sr;
        int rg = t0 + r; rg = (rg < S_) ? rg : (S_ - 1);
        float4 v = *(const float4*)(xcol + (size_t)rg * CIN_);
        bf16x4 o4; o4[0]=(__bf16)v.x; o4[1]=(__bf16)v.y; o4[2]=(__bf16)v.z; o4[3]=(__bf16)v.w;
        *(bf16x4*)(As + r * 32 + sc) = o4;
      }
      if (tid < 128) {  // tail rows 128..143
        int r = 128 + sr;
        int rg = t0 + r; rg = (rg < S_) ? rg : (S_ - 1);
        float4 v = *(const float4*)(xcol + (size_t)rg * CIN_);
        bf16x4 o4; o4[0]=(__bf16)v.x; o4[1]=(__bf16)v.y; o4[2]=(__bf16)v.z; o4[3]=(__bf16)v.w;
        *(bf16x4*)(As + r * 32 + sc) = o4;
      }
    }

    for (int kk = 0; kk < K_; ++kk) {
      if (kk) __syncthreads();  // previous kk's Bs reads done

      // ---- Stage B: wt[o0+row][kk*256 + i0 + col], 8 KB ----
      const __bf16* wcol = wt + (size_t)kk * CIN_ + i0 + bc;
      #pragma unroll
      for (int p = 0; p < 2; p++) {
        int orow = o0 + p * 64 + br;
        gload_lds16(wcol + (size_t)orow * RTOT_,
                    (void*)(Bs + (p * 64 + w * 16) * 32));
      }

      __syncthreads();  // drains vm/lgkm: As (first iter) + Bs valid

      bf16x8 af[4], bfrag[4];
      #pragma unroll
      for (int jm = 0; jm < 4; jm++) {
        int row = kk + wm * 64 + jm * 16 + n16;    // A[m=lane&15][k=q*8+j]
        af[jm] = *(const bf16x8*)(As + row * 32 + q * 8);
      }
      #pragma unroll
      for (int jn = 0; jn < 4; jn++) {
        int row = wn * 64 + jn * 16 + n16;         // B^T[n=lane&15][k=q*8+j]
        bfrag[jn] = *(const bf16x8*)(Bs + row * 32 + q * 8);
      }
      #pragma unroll
      for (int jm = 0; jm < 4; jm++)
        #pragma unroll
        for (int jn = 0; jn < 4; jn++)
          acc[jm][jn] = __builtin_amdgcn_mfma_f32_16x16x32_bf16(af[jm], bfrag[jn], acc[jm][jn], 0, 0, 0);
    }
  }

  // ---- Epilogue: C/D layout col = lane&15, row = (lane>>4)*4 + reg ----
  float* obase = out + (size_t)b * TOUT_ * COUT_;
  #pragma unroll
  for (int jm = 0; jm < 4; jm++) {
    #pragma unroll
    for (int r = 0; r < 4; r++) {
      int t = t0 + wm * 64 + jm * 16 + q * 4 + r;
      if (t < TOUT_) {
        float* orow = obase + (size_t)t * COUT_ + o0 + wn * 64 + n16;
        #pragma unroll
        for (int jn = 0; jn < 4; jn++)
          orow[jn * 16] = acc[jm][jn][r];
      }
    }
  }
}

// ---------------------------------------------------------------------------
extern "C" void kernel_launch(void* const* d_in, const int* in_sizes, int n_in,
                              void* d_out, int out_size, void* d_ws, size_t ws_size,
                              hipStream_t stream) {
  const float* x  = (const float*)d_in[0];
  const float* wr = (const float*)d_in[1];
  const float* wi = (const float*)d_in[2];
  const float* ph = (const float*)d_in[3];
  float* out = (float*)d_out;

  __bf16* wt = (__bf16*)d_ws;  // 2 MB only

  build_wt_kernel<<<dim3((COUT_ * CIN_) / 256), dim3(256), 0, stream>>>(wr, wi, ph, wt);
  conv_mfma_kernel<<<dim3(B_ * 16 * 2), dim3(256), 0, stream>>>(x, wt, out);
}